// Round 8
// baseline (963.130 us; speedup 1.0000x reference)
//
#include <hip/hip_runtime.h>

// ROUND 8: bit-exact np-d2 hunt. History: no-FMA dot asc/desc -> 0.25 (R3/R6);
// exact-f64 true order -> 0.25 (R5); asc-FMA dot -> 0.175 (R7, FIRST CHANGE).
// => reference d2 uses FMA-contracted arithmetic (XLA/BLAS lowering).
// Analytic elimination: 2*dot is exact, so the d2 subtraction has a unique
// rounding — the only remaining free variable is sq. This round: sq also
// FMA-contracted ascending (fused mul+reduce loop, LLVM contract):
//   sq  = fmaf(z,z, fmaf(y,y, rn(x*x)))
//   dot = fmaf(z,z', fmaf(y,y', rn(x*x')))
//   d2  = rn( rn(sq_q + sq_c) - 2*dot )
#define NPTS 8192
#define KNN  11
#define QPB  64            // one wave per block, one thread per query

__global__ __launch_bounds__(64) void knn_brute(
    const float* __restrict__ pos,
    const float* __restrict__ vel,
    const float* __restrict__ initc,
    const float* __restrict__ W1,
    const float* __restrict__ b1,
    const float* __restrict__ W2,
    const float* __restrict__ b2,
    const float* __restrict__ W3,
    const float* __restrict__ b3,
    float* __restrict__ out) {

    __shared__ float sx[NPTS];              // whole batch, SoA
    __shared__ float sy[NPTS];
    __shared__ float sz[NPTS];
    __shared__ float ssq[NPTS];             // reference-rounded sq per point
    __shared__ float sW12[66 * 16 + 16];    // fold scratch
    __shared__ float sW[405];               // Weff[396] + bias[6] + init[3]

    const int tid = threadIdx.x;
    const int b   = blockIdx.x >> 7;        // 128 blocks per batch
    const int n0  = (blockIdx.x & 127) * QPB;
    const int q   = n0 + tid;

    const float* posb = pos + b * NPTS * 3;
    const float* velb = vel + b * NPTS * 3;

    // ---- stage entire batch positions into LDS (SoA) + contracted sq
    for (int a = tid; a < NPTS; a += QPB) {
        float x = posb[a * 3 + 0];
        float y = posb[a * 3 + 1];
        float z = posb[a * 3 + 2];
        sx[a] = x; sy[a] = y; sz[a] = z;
        // fused mul+reduce with FMA contraction, ascending k:
        ssq[a] = __fmaf_rn(z, z, __fmaf_rn(y, y, __fmul_rn(x, x)));
    }

    // ---- fold MLP (no activation): Weff = W1@W2@W3, bias = ((b1@W2)+b2)@W3+b3
    for (int e = tid; e < 66 * 16; e += QPB) {
        int r = e >> 4, c = e & 15;
        float s = 0.f;
        for (int j = 0; j < 32; ++j) s += W1[r * 32 + j] * W2[j * 16 + c];
        sW12[e] = s;
    }
    if (tid < 16) {
        float s = b2[tid];
        for (int j = 0; j < 32; ++j) s += b1[j] * W2[j * 16 + tid];
        sW12[66 * 16 + tid] = s;
    }
    if (tid < 3) sW[402 + tid] = initc[b * 3 + tid];
    __syncthreads();
    for (int e = tid; e < 66 * 6; e += QPB) {
        int r = e / 6, c = e - r * 6;
        float s = 0.f;
        for (int j = 0; j < 16; ++j) s += sW12[r * 16 + j] * W3[j * 6 + c];
        sW[e] = s;
    }
    if (tid < 6) {
        float s = b3[tid];
        for (int j = 0; j < 16; ++j) s += sW12[66 * 16 + j] * W3[j * 6 + tid];
        sW[396 + tid] = s;
    }
    __syncthreads();

    const float qx = sx[q], qy = sy[q], qz = sz[q];
    const float sqq = ssq[q];

    float d[KNN]; int id[KNN];
#pragma unroll
    for (int m = 0; m < KNN; ++m) { d[m] = 3.0e38f; id[m] = 0x7FFFFFFF; }

    // ---- f32 full scan: FMA-contracted dot (ascending), reference-emulated.
    for (int j = 0; j < NPTS; ++j) {
        float dot = __fmaf_rn(qz, sz[j],
                    __fmaf_rn(qy, sy[j],
                    __fmul_rn(qx, sx[j])));
        float d2 = __fsub_rn(__fadd_rn(sqq, ssq[j]), __fmul_rn(2.0f, dot));
        if (d2 < d[KNN - 1]) {              // strict <: ties keep lower index
            bool c = true;
#pragma unroll
            for (int s = KNN - 1; s >= 1; --s) {
                bool cp = d2 < d[s - 1];
                d[s]  = cp ? d[s - 1] : (c ? d2 : d[s]);
                id[s] = cp ? id[s - 1] : (c ? j  : id[s]);
                c = cp;
            }
            if (c) { d[0] = d2; id[0] = j; }
        }
    }

    // ---- features + folded MLP (per-thread; ids already rank-sorted)
    float acc[6];
#pragma unroll
    for (int c = 0; c < 6; ++c) acc[c] = sW[396 + c];

    for (int r = 0; r < KNN; ++r) {
        int bi = id[r];
        int bg = ((unsigned)bi < (unsigned)NPTS) ? bi : 0;   // defensive

        // velocity features: slots [r*3 .. r*3+2]
        const float* vp = velb + bg * 3;
        float vx = vp[0], vy = vp[1], vz = vp[2];
        const float* w = &sW[r * 18];
#pragma unroll
        for (int c = 0; c < 6; ++c) {
            acc[c] += vx * w[c];
            acc[c] += vy * w[6 + c];
            acc[c] += vz * w[12 + c];
        }
        // offset features: slots [33+(r-1)*3 ..], rank 0 (self) excluded
        if (r >= 1) {
            float ox = sx[bg] - qx;
            float oy = sy[bg] - qy;
            float oz = sz[bg] - qz;
            const float* w2 = &sW[(33 + (r - 1) * 3) * 6];
#pragma unroll
            for (int c = 0; c < 6; ++c) {
                acc[c] += ox * w2[c];
                acc[c] += oy * w2[6 + c];
                acc[c] += oz * w2[12 + c];
            }
        }
    }
    // init_config features: slots [63..65]
#pragma unroll
    for (int k3 = 0; k3 < 3; ++k3) {
        const float* w3 = &sW[(63 + k3) * 6];
        float iv = sW[402 + k3];
#pragma unroll
        for (int c = 0; c < 6; ++c) acc[c] += iv * w3[c];
    }
    acc[0] += qx; acc[1] += qy; acc[2] += qz;

    float* op = out + (b * NPTS + q) * 6;
#pragma unroll
    for (int c = 0; c < 6; ++c) op[c] = acc[c];
}

extern "C" void kernel_launch(void* const* d_in, const int* in_sizes, int n_in,
                              void* d_out, int out_size, void* d_ws, size_t ws_size,
                              hipStream_t stream) {
    (void)in_sizes; (void)n_in; (void)out_size; (void)d_ws; (void)ws_size;
    const float* pos   = (const float*)d_in[0];
    const float* vel   = (const float*)d_in[1];
    const float* initc = (const float*)d_in[2];
    const float* W1    = (const float*)d_in[3];
    const float* b1    = (const float*)d_in[4];
    const float* W2    = (const float*)d_in[5];
    const float* b2    = (const float*)d_in[6];
    const float* W3    = (const float*)d_in[7];
    const float* b3    = (const float*)d_in[8];
    float* out = (float*)d_out;

    knn_brute<<<256, QPB, 0, stream>>>(pos, vel, initc, W1, b1, W2, b2, W3, b3, out);
}

// Round 9
// 251.891 us; speedup vs baseline: 3.8236x; 3.8236x over previous
//
#include <hip/hip_runtime.h>

// B=2, N=8192, K=10, I=3, LEN_IN=66. All buffers f32.
// LOCKED correctness recipe (R8, passed, absmax 0.0625):
//   sq  = fmaf(z,z, fmaf(y,y, rn(x*x)))          (asc FMA)
//   dot = fmaf(z,z', fmaf(y,y', rn(x*x')))       (asc FMA)
//   d2  = single-rounding of (sq_q + sq_c) - 2*dot   [fma(-2,dot,s) == sub form]
//   selection: strict <, stable lowest-index-first (lexicographic (d2,idx))
// R9: performance restructure only — selection semantics bit-identical.
#define NPTS   8192
#define KNN    11
#define QPB    64          // queries per block (one per lane)
#define NSLICE 4           // candidate slices (one per wave)
#define SLEN   (NPTS / NSLICE)   // 2048
#define DEPTH  12          // per-lane LDS push-buffer entries
#define TRIG   9           // flush when any lane cnt >= TRIG (4 pushes headroom)

__global__ __launch_bounds__(256) void knn_mlp(
    const float* __restrict__ pos,
    const float* __restrict__ vel,
    const float* __restrict__ initc,
    const float* __restrict__ W1,
    const float* __restrict__ b1,
    const float* __restrict__ W2,
    const float* __restrict__ b2,
    const float* __restrict__ W3,
    const float* __restrict__ b3,
    float* __restrict__ out) {

    __shared__ __align__(16) float tile[NPTS * 3];          // 96KB packed float3
    __shared__ __align__(16) unsigned long long region[256 * DEPTH]; // 24KB, phased:
    // phase0: fold scratch (4.3KB) | phase1: push buffers (24KB) | phase2: pd/pi (22KB)
    __shared__ float sW[405];                               // Weff[396]+bias[6]+init[3]

    const int tid  = threadIdx.x;
    const int lane = tid & 63;
    const int wave = tid >> 6;
    const int b    = blockIdx.x >> 7;           // 128 blocks per batch
    const int n0   = (blockIdx.x & 127) * QPB;
    const int q    = n0 + lane;

    const float* posb = pos + b * NPTS * 3;
    const float* velb = vel + b * NPTS * 3;

    // ---- stage full position tile (layout identical to global: [N][3])
    {
        const float4* g4 = (const float4*)posb;     // 6144 float4
        float4* t4 = (float4*)tile;
#pragma unroll
        for (int i = 0; i < (NPTS * 3 / 4) / 256; ++i)   // 24 iters
            t4[i * 256 + tid] = g4[i * 256 + tid];
    }

    // ---- fold MLP stage 1 (scratch in region): W12 = W1@W2, b12 = b1@W2+b2
    float* sW12 = (float*)region;
    for (int e = tid; e < 66 * 16; e += 256) {
        int r = e >> 4, c = e & 15;
        float s = 0.f;
        for (int j = 0; j < 32; ++j) s += W1[r * 32 + j] * W2[j * 16 + c];
        sW12[e] = s;
    }
    if (tid < 16) {
        float s = b2[tid];
        for (int j = 0; j < 32; ++j) s += b1[j] * W2[j * 16 + tid];
        sW12[66 * 16 + tid] = s;
    }
    if (tid < 3) sW[402 + tid] = initc[b * 3 + tid];
    __syncthreads();
    // ---- fold stage 2: Weff = W12@W3, bias = b12@W3 + b3
    for (int e = tid; e < 66 * 6; e += 256) {
        int r = e / 6, c = e - r * 6;
        float s = 0.f;
        for (int j = 0; j < 16; ++j) s += sW12[r * 16 + j] * W3[j * 6 + c];
        sW[e] = s;
    }
    if (tid < 6) {
        float s = b3[tid];
        for (int j = 0; j < 16; ++j) s += sW12[66 * 16 + j] * W3[j * 6 + tid];
        sW[396 + tid] = s;
    }
    __syncthreads();   // fold scratch reads done -> region becomes push buffers

    const float qx = tile[q * 3 + 0];
    const float qy = tile[q * 3 + 1];
    const float qz = tile[q * 3 + 2];
    const float sqq = __fmaf_rn(qz, qz, __fmaf_rn(qy, qy, __fmul_rn(qx, qx)));

    float d[KNN]; int id[KNN];
#pragma unroll
    for (int m = 0; m < KNN; ++m) { d[m] = 3.0e38f; id[m] = 0x7FFFFFFF; }

    float thr = 3.0e38f;       // stale copy of d[10]; only over-buffers
    int cnt = 0;
    unsigned long long* mybuf = region + tid * DEPTH;

    auto flush = [&]() {
#pragma unroll 1
        for (int k = 0; k < DEPTH; ++k) {
            if (k < cnt) {
                unsigned long long e = mybuf[k];
                float nd = __uint_as_float((unsigned)(e >> 32));
                int   nj = (int)(unsigned)(e & 0xFFFFFFFFull);
                if (nd < d[KNN - 1]) {          // strict <: stable
                    bool c = true;
#pragma unroll
                    for (int s = KNN - 1; s >= 1; --s) {
                        bool cp = nd < d[s - 1];
                        d[s]  = cp ? d[s - 1] : (c ? nd : d[s]);
                        id[s] = cp ? id[s - 1] : (c ? nj : id[s]);
                        c = cp;
                    }
                    if (c) { d[0] = nd; id[0] = nj; }
                }
            }
        }
        cnt = 0;
        thr = d[KNN - 1];
    };

    auto proc = [&](float cx, float cy, float cz, int j) {
        float sqc = __fmaf_rn(cz, cz, __fmaf_rn(cy, cy, __fmul_rn(cx, cx)));
        float dot = __fmaf_rn(qz, cz, __fmaf_rn(qy, cy, __fmul_rn(qx, cx)));
        float d2  = __fmaf_rn(-2.0f, dot, __fadd_rn(sqq, sqc)); // == rn(s-2dot)
        if (d2 < thr) {
            mybuf[cnt] = (((unsigned long long)__float_as_uint(d2)) << 32)
                         | (unsigned)j;
            ++cnt;
        }
    };

    const int base = wave * SLEN;
    for (int m = 0; m < SLEN; m += 4) {
        int j = base + m;                           // mult of 4 -> 16B aligned
        const float4* cp = (const float4*)&tile[j * 3];
        float4 A = cp[0], B = cp[1], C = cp[2];     // 12 floats = 4 candidates
        proc(A.x, A.y, A.z, j + 0);
        proc(A.w, B.x, B.y, j + 1);
        proc(B.z, B.w, C.x, j + 2);
        proc(C.y, C.z, C.w, j + 3);
        if (__any(cnt >= TRIG)) flush();            // wave-uniform rare path
    }
    flush();                                        // final

    __syncthreads();   // all scans done -> region becomes merge lists
    float* pd = (float*)region;                     // [256][11] f32
    int*   pi = (int*)(pd + 256 * KNN);             // [256][11] i32
#pragma unroll
    for (int m = 0; m < KNN; ++m) { pd[tid * KNN + m] = d[m]; pi[tid * KNN + m] = id[m]; }
    __syncthreads();

    if (tid < QPB) {
        // 4-way merge, lexicographic (d2, idx) == global stable top-11.
        int p[NSLICE]; float hd[NSLICE]; int hi[NSLICE];
#pragma unroll
        for (int s = 0; s < NSLICE; ++s) {
            p[s]  = 0;
            hd[s] = pd[(s * 64 + tid) * KNN];
            hi[s] = pi[(s * 64 + tid) * KNN];
        }
        float acc[6];
#pragma unroll
        for (int c = 0; c < 6; ++c) acc[c] = sW[396 + c];

        for (int r = 0; r < KNN; ++r) {
            float bd = 3.9e38f; int bi = 0x7FFFFFFF; int bs = 0;
#pragma unroll
            for (int s = 0; s < NSLICE; ++s) {
                bool better = (hd[s] < bd) || (hd[s] == bd && hi[s] < bi);
                bs = better ? s : bs;
                bi = better ? hi[s] : bi;
                bd = better ? hd[s] : bd;
            }
            {   // advance winning slice head
                int pp = ++p[bs];
                if (pp < KNN) {
                    hd[bs] = pd[(bs * 64 + tid) * KNN + pp];
                    hi[bs] = pi[(bs * 64 + tid) * KNN + pp];
                } else { hd[bs] = 3.9e38f; hi[bs] = 0x7FFFFFFF; }
            }

            int bg = ((unsigned)bi < (unsigned)NPTS) ? bi : 0;   // defensive

            // velocity features: slots [r*3 .. r*3+2]
            const float* vp = velb + bg * 3;
            float vx = vp[0], vy = vp[1], vz = vp[2];
            const float* w = &sW[r * 18];
#pragma unroll
            for (int c = 0; c < 6; ++c) {
                acc[c] += vx * w[c];
                acc[c] += vy * w[6 + c];
                acc[c] += vz * w[12 + c];
            }
            // offset features (positions from LDS tile): rank 0 = self excluded
            if (r >= 1) {
                float ox = tile[bg * 3 + 0] - qx;
                float oy = tile[bg * 3 + 1] - qy;
                float oz = tile[bg * 3 + 2] - qz;
                const float* w2 = &sW[(33 + (r - 1) * 3) * 6];
#pragma unroll
                for (int c = 0; c < 6; ++c) {
                    acc[c] += ox * w2[c];
                    acc[c] += oy * w2[6 + c];
                    acc[c] += oz * w2[12 + c];
                }
            }
        }
        // init_config features: slots [63..65]
#pragma unroll
        for (int k3 = 0; k3 < 3; ++k3) {
            const float* w3 = &sW[(63 + k3) * 6];
            float iv = sW[402 + k3];
#pragma unroll
            for (int c = 0; c < 6; ++c) acc[c] += iv * w3[c];
        }
        acc[0] += qx; acc[1] += qy; acc[2] += qz;

        float* op = out + (b * NPTS + q) * 6;
#pragma unroll
        for (int c = 0; c < 6; ++c) op[c] = acc[c];
    }
}

extern "C" void kernel_launch(void* const* d_in, const int* in_sizes, int n_in,
                              void* d_out, int out_size, void* d_ws, size_t ws_size,
                              hipStream_t stream) {
    (void)in_sizes; (void)n_in; (void)out_size; (void)d_ws; (void)ws_size;
    const float* pos   = (const float*)d_in[0];
    const float* vel   = (const float*)d_in[1];
    const float* initc = (const float*)d_in[2];
    const float* W1    = (const float*)d_in[3];
    const float* b1    = (const float*)d_in[4];
    const float* W2    = (const float*)d_in[5];
    const float* b2    = (const float*)d_in[6];
    const float* W3    = (const float*)d_in[7];
    const float* b3    = (const float*)d_in[8];
    float* out = (float*)d_out;

    knn_mlp<<<256, 256, 0, stream>>>(pos, vel, initc, W1, b1, W2, b2, W3, b3, out);
}

// Round 10
// 192.169 us; speedup vs baseline: 5.0119x; 1.3108x over previous
//
#include <hip/hip_runtime.h>

// B=2, N=8192, K=10, I=3, LEN_IN=66. All buffers f32.
// LOCKED correctness recipe (R8/R9, passed, absmax 0.0625):
//   sq  = fmaf(z,z, fmaf(y,y, rn(x*x)))          (asc FMA)
//   dot = fmaf(z,z', fmaf(y,y', rn(x*x')))       (asc FMA)
//   d2  = fmaf(-2,dot, rn(sq_q + sq_c))          (== single-rounded sub form)
//   selection: strict <, stable lowest-index-first (lexicographic (d2,idx))
// R10: 512-thread blocks -> 8 waves/CU (2/SIMD) for latency hiding. Scan
// semantics bit-identical; merge widened 4->8 way.
#define NPTS   8192
#define KNN    11
#define QPB    64          // queries per block (one per lane)
#define NTHR   512
#define NSLICE 8           // candidate slices (one per wave)
#define SLEN   (NPTS / NSLICE)   // 1024
#define DEPTH  12          // per-lane LDS push-buffer entries
#define TRIG   9           // flush when any lane cnt >= TRIG (4 pushes headroom)

__global__ __launch_bounds__(NTHR) void knn_mlp(
    const float* __restrict__ pos,
    const float* __restrict__ vel,
    const float* __restrict__ initc,
    const float* __restrict__ W1,
    const float* __restrict__ b1,
    const float* __restrict__ W2,
    const float* __restrict__ b2,
    const float* __restrict__ W3,
    const float* __restrict__ b3,
    float* __restrict__ out) {

    __shared__ __align__(16) float tile[NPTS * 3];            // 96KB packed float3
    __shared__ __align__(16) unsigned long long region[NTHR * DEPTH]; // 48KB, phased:
    // phase0: fold scratch (4.3KB) | phase1: push buffers (48KB) | phase2: pd/pi (45KB)
    __shared__ float sW[405];                                 // Weff[396]+bias[6]+init[3]

    const int tid  = threadIdx.x;
    const int lane = tid & 63;
    const int wave = tid >> 6;
    const int b    = blockIdx.x >> 7;           // 128 blocks per batch
    const int n0   = (blockIdx.x & 127) * QPB;
    const int q    = n0 + lane;

    const float* posb = pos + b * NPTS * 3;
    const float* velb = vel + b * NPTS * 3;

    // ---- stage full position tile (layout identical to global: [N][3])
    {
        const float4* g4 = (const float4*)posb;     // 6144 float4
        float4* t4 = (float4*)tile;
#pragma unroll
        for (int i = 0; i < (NPTS * 3 / 4) / NTHR; ++i)   // 12 iters
            t4[i * NTHR + tid] = g4[i * NTHR + tid];
    }

    // ---- fold MLP stage 1 (scratch in region): W12 = W1@W2, b12 = b1@W2+b2
    float* sW12 = (float*)region;
    for (int e = tid; e < 66 * 16; e += NTHR) {
        int r = e >> 4, c = e & 15;
        float s = 0.f;
        for (int j = 0; j < 32; ++j) s += W1[r * 32 + j] * W2[j * 16 + c];
        sW12[e] = s;
    }
    if (tid < 16) {
        float s = b2[tid];
        for (int j = 0; j < 32; ++j) s += b1[j] * W2[j * 16 + tid];
        sW12[66 * 16 + tid] = s;
    }
    if (tid < 3) sW[402 + tid] = initc[b * 3 + tid];
    __syncthreads();
    // ---- fold stage 2: Weff = W12@W3, bias = b12@W3 + b3
    for (int e = tid; e < 66 * 6; e += NTHR) {
        int r = e / 6, c = e - r * 6;
        float s = 0.f;
        for (int j = 0; j < 16; ++j) s += sW12[r * 16 + j] * W3[j * 6 + c];
        sW[e] = s;
    }
    if (tid < 6) {
        float s = b3[tid];
        for (int j = 0; j < 16; ++j) s += sW12[66 * 16 + j] * W3[j * 6 + tid];
        sW[396 + tid] = s;
    }
    __syncthreads();   // fold scratch reads done -> region becomes push buffers

    const float qx = tile[q * 3 + 0];
    const float qy = tile[q * 3 + 1];
    const float qz = tile[q * 3 + 2];
    const float sqq = __fmaf_rn(qz, qz, __fmaf_rn(qy, qy, __fmul_rn(qx, qx)));

    float d[KNN]; int id[KNN];
#pragma unroll
    for (int m = 0; m < KNN; ++m) { d[m] = 3.0e38f; id[m] = 0x7FFFFFFF; }

    float thr = 3.0e38f;       // stale copy of d[10]; only over-buffers
    int cnt = 0;
    unsigned long long* mybuf = region + tid * DEPTH;

    auto flush = [&]() {
#pragma unroll 1
        for (int k = 0; k < DEPTH; ++k) {
            if (k < cnt) {
                unsigned long long e = mybuf[k];
                float nd = __uint_as_float((unsigned)(e >> 32));
                int   nj = (int)(unsigned)(e & 0xFFFFFFFFull);
                if (nd < d[KNN - 1]) {          // strict <: stable
                    bool c = true;
#pragma unroll
                    for (int s = KNN - 1; s >= 1; --s) {
                        bool cp = nd < d[s - 1];
                        d[s]  = cp ? d[s - 1] : (c ? nd : d[s]);
                        id[s] = cp ? id[s - 1] : (c ? nj : id[s]);
                        c = cp;
                    }
                    if (c) { d[0] = nd; id[0] = nj; }
                }
            }
        }
        cnt = 0;
        thr = d[KNN - 1];
    };

    auto proc = [&](float cx, float cy, float cz, int j) {
        float sqc = __fmaf_rn(cz, cz, __fmaf_rn(cy, cy, __fmul_rn(cx, cx)));
        float dot = __fmaf_rn(qz, cz, __fmaf_rn(qy, cy, __fmul_rn(qx, cx)));
        float d2  = __fmaf_rn(-2.0f, dot, __fadd_rn(sqq, sqc)); // == rn(s-2dot)
        if (d2 < thr) {
            mybuf[cnt] = (((unsigned long long)__float_as_uint(d2)) << 32)
                         | (unsigned)j;
            ++cnt;
        }
    };

    const int base = wave * SLEN;
    for (int m = 0; m < SLEN; m += 4) {
        int j = base + m;                           // mult of 4 -> 16B aligned
        const float4* cp = (const float4*)&tile[j * 3];
        float4 A = cp[0], B = cp[1], C = cp[2];     // 12 floats = 4 candidates
        proc(A.x, A.y, A.z, j + 0);
        proc(A.w, B.x, B.y, j + 1);
        proc(B.z, B.w, C.x, j + 2);
        proc(C.y, C.z, C.w, j + 3);
        if (__any(cnt >= TRIG)) flush();            // wave-uniform rare path
    }
    flush();                                        // final

    __syncthreads();   // all scans done -> region becomes merge lists
    float* pd = (float*)region;                     // [NTHR][11] f32
    int*   pi = (int*)(pd + NTHR * KNN);            // [NTHR][11] i32
#pragma unroll
    for (int m = 0; m < KNN; ++m) { pd[tid * KNN + m] = d[m]; pi[tid * KNN + m] = id[m]; }
    __syncthreads();

    if (tid < QPB) {
        // 8-way merge, lexicographic (d2, idx) == global stable top-11.
        int p[NSLICE]; float hd[NSLICE]; int hi[NSLICE];
#pragma unroll
        for (int s = 0; s < NSLICE; ++s) {
            p[s]  = 0;
            hd[s] = pd[(s * 64 + tid) * KNN];
            hi[s] = pi[(s * 64 + tid) * KNN];
        }
        float acc[6];
#pragma unroll
        for (int c = 0; c < 6; ++c) acc[c] = sW[396 + c];

        for (int r = 0; r < KNN; ++r) {
            float bd = 3.9e38f; int bi = 0x7FFFFFFF; int bs = 0;
#pragma unroll
            for (int s = 0; s < NSLICE; ++s) {
                bool better = (hd[s] < bd) || (hd[s] == bd && hi[s] < bi);
                bs = better ? s : bs;
                bi = better ? hi[s] : bi;
                bd = better ? hd[s] : bd;
            }
            {   // advance winning slice head
                int pp = ++p[bs];
                if (pp < KNN) {
                    hd[bs] = pd[(bs * 64 + tid) * KNN + pp];
                    hi[bs] = pi[(bs * 64 + tid) * KNN + pp];
                } else { hd[bs] = 3.9e38f; hi[bs] = 0x7FFFFFFF; }
            }

            int bg = ((unsigned)bi < (unsigned)NPTS) ? bi : 0;   // defensive

            // velocity features: slots [r*3 .. r*3+2]
            const float* vp = velb + bg * 3;
            float vx = vp[0], vy = vp[1], vz = vp[2];
            const float* w = &sW[r * 18];
#pragma unroll
            for (int c = 0; c < 6; ++c) {
                acc[c] += vx * w[c];
                acc[c] += vy * w[6 + c];
                acc[c] += vz * w[12 + c];
            }
            // offset features (positions from LDS tile): rank 0 = self excluded
            if (r >= 1) {
                float ox = tile[bg * 3 + 0] - qx;
                float oy = tile[bg * 3 + 1] - qy;
                float oz = tile[bg * 3 + 2] - qz;
                const float* w2 = &sW[(33 + (r - 1) * 3) * 6];
#pragma unroll
                for (int c = 0; c < 6; ++c) {
                    acc[c] += ox * w2[c];
                    acc[c] += oy * w2[6 + c];
                    acc[c] += oz * w2[12 + c];
                }
            }
        }
        // init_config features: slots [63..65]
#pragma unroll
        for (int k3 = 0; k3 < 3; ++k3) {
            const float* w3 = &sW[(63 + k3) * 6];
            float iv = sW[402 + k3];
#pragma unroll
            for (int c = 0; c < 6; ++c) acc[c] += iv * w3[c];
        }
        acc[0] += qx; acc[1] += qy; acc[2] += qz;

        float* op = out + (b * NPTS + q) * 6;
#pragma unroll
        for (int c = 0; c < 6; ++c) op[c] = acc[c];
    }
}

extern "C" void kernel_launch(void* const* d_in, const int* in_sizes, int n_in,
                              void* d_out, int out_size, void* d_ws, size_t ws_size,
                              hipStream_t stream) {
    (void)in_sizes; (void)n_in; (void)out_size; (void)d_ws; (void)ws_size;
    const float* pos   = (const float*)d_in[0];
    const float* vel   = (const float*)d_in[1];
    const float* initc = (const float*)d_in[2];
    const float* W1    = (const float*)d_in[3];
    const float* b1    = (const float*)d_in[4];
    const float* W2    = (const float*)d_in[5];
    const float* b2    = (const float*)d_in[6];
    const float* W3    = (const float*)d_in[7];
    const float* b3    = (const float*)d_in[8];
    float* out = (float*)d_out;

    knn_mlp<<<256, NTHR, 0, stream>>>(pos, vel, initc, W1, b1, W2, b2, W3, b3, out);
}